// Round 13
// baseline (192.328 us; speedup 1.0000x reference)
//
#include <hip/hip_runtime.h>
#include <math.h>

#define N 16384
#define KNN 16
#define G 16
#define NCELL 4096

typedef __attribute__((ext_vector_type(8))) short bf16x8;
typedef __attribute__((ext_vector_type(4))) float f32x4;
typedef unsigned short ushort_t;
typedef unsigned long long u64;

__device__ __forceinline__ float lrelu(float a) { return a > 0.f ? a : 0.01f * a; }

__device__ __forceinline__ ushort_t f2bf(float f) {
  unsigned u = __float_as_uint(f);
  u += 0x7FFF + ((u >> 16) & 1);
  return (ushort_t)(u >> 16);
}
__device__ __forceinline__ float bf2f(ushort_t h) {
  return __uint_as_float((unsigned)h << 16);
}
__device__ __forceinline__ int lanerank(u64 mask) {
  return __builtin_amdgcn_mbcnt_hi((unsigned)(mask >> 32),
         __builtin_amdgcn_mbcnt_lo((unsigned)mask, 0));
}
__device__ __forceinline__ int cellof(float x) {
  int c = (int)(x * (float)G);
  return c < 0 ? 0 : (c > G - 1 ? G - 1 : c);
}

// ---------------------------------------------------------------------------
// prepw: prep (blocks 0..255, + cell histogram) + weight conv (256..603).
// ---------------------------------------------------------------------------
#define PPB 64
__global__ __launch_bounds__(256) void prepw_kernel(
    const float* __restrict__ img, const float* __restrict__ cloud,
    const float* __restrict__ p1w, const float* __restrict__ p1b,
    const float* __restrict__ p2w, const float* __restrict__ p2b,
    const float* __restrict__ ps1w, const float* __restrict__ ps2w,
    const float* __restrict__ c1w, const float* __restrict__ c2w,
    const float* __restrict__ fw,
    float4* __restrict__ pts4, ushort_t* __restrict__ cfh,
    ushort_t* __restrict__ imfh,
    ushort_t* __restrict__ w1h, ushort_t* __restrict__ w2h,
    ushort_t* __restrict__ c1h, ushort_t* __restrict__ c2h,
    float* __restrict__ fwp2, int* __restrict__ count) {
  int t = threadIdx.x;
  if (blockIdx.x >= 256) {
    int e = (blockIdx.x - 256) * 256 + t;
    if (e < 32768) w1h[e] = f2bf(ps1w[e]);
    else if (e < 65536) w2h[e - 32768] = f2bf(ps2w[e - 32768]);
    else if (e < 67584) c1h[e - 65536] = f2bf(c1w[e - 65536]);
    else if (e < 75776) c2h[e - 67584] = f2bf(c2w[e - 67584]);
    else if (e < 89088) {
      int e2 = e - 75776;
      int j4 = e2 >> 7, r2 = e2 & 127;
      int ch = r2 >> 2, sub = r2 & 3;
      fwp2[e2] = fw[ch * 416 + j4 * 4 + sub];
    }
    return;
  }
  __shared__ alignas(16) float w2t[64 * 132];
  __shared__ alignas(16) float hs[PPB * 68];
  __shared__ alignas(16) float w1s[192];
  __shared__ alignas(16) float b1s[64];
  __shared__ alignas(16) float b2s[128];
  __shared__ float ptmp[PPB * 3];
  __shared__ float psx[PPB], psy[PPB], psz[PPB];
  int pb = blockIdx.x * PPB;

  for (int e = t; e < 128 * 64; e += 256) {
    int ch = e >> 6, k = e & 63;
    w2t[k * 132 + ch] = p2w[e];
  }
  if (t < 192) w1s[t] = p1w[t];
  if (t < 64) b1s[t] = p1b[t];
  if (t < 128) b2s[t] = p2b[t];
  if (t < PPB * 3) ptmp[t] = cloud[pb * 3 + t];
  __syncthreads();
  if (t < PPB) {
    float x = ptmp[t * 3], y = ptmp[t * 3 + 1], z = ptmp[t * 3 + 2];
    psx[t] = x; psy[t] = y; psz[t] = z;
    pts4[pb + t] = make_float4(x, y, z, x * x + y * y + z * z);
    int cid = ((cellof(z) << 4) | cellof(y)) << 4 | cellof(x);
    atomicAdd(&count[cid], 1);
  }
  for (int e = t; e < 32 * PPB; e += 256) {
    int c = e >> 6, p = e & 63;
    imfh[(size_t)(pb + p) * 32 + c] = f2bf(img[(size_t)c * N + pb + p]);
  }
  __syncthreads();
  for (int e = t; e < PPB * 64; e += 256) {
    int pt_ = e >> 6, ch = e & 63;
    float a = b1s[ch] + psx[pt_] * w1s[ch * 3] + psy[pt_] * w1s[ch * 3 + 1] +
              psz[pt_] * w1s[ch * 3 + 2];
    hs[pt_ * 68 + ch] = lrelu(a);
  }
  __syncthreads();
  for (int e = t; e < PPB * 32; e += 256) {
    int pt_ = e >> 5, c4 = (e & 31) << 2;
    float4 acc = *(const float4*)&b2s[c4];
    const float* hrow = &hs[pt_ * 68];
    #pragma unroll
    for (int k = 0; k < 64; k += 4) {
      float4 h4 = *(const float4*)&hrow[k];
      float4 w0 = *(const float4*)&w2t[(k + 0) * 132 + c4];
      float4 w1_ = *(const float4*)&w2t[(k + 1) * 132 + c4];
      float4 w2_ = *(const float4*)&w2t[(k + 2) * 132 + c4];
      float4 w3 = *(const float4*)&w2t[(k + 3) * 132 + c4];
      acc.x = fmaf(h4.x, w0.x, fmaf(h4.y, w1_.x, fmaf(h4.z, w2_.x, fmaf(h4.w, w3.x, acc.x))));
      acc.y = fmaf(h4.x, w0.y, fmaf(h4.y, w1_.y, fmaf(h4.z, w2_.y, fmaf(h4.w, w3.y, acc.y))));
      acc.z = fmaf(h4.x, w0.z, fmaf(h4.y, w1_.z, fmaf(h4.z, w2_.z, fmaf(h4.w, w3.z, acc.z))));
      acc.w = fmaf(h4.x, w0.w, fmaf(h4.y, w1_.w, fmaf(h4.z, w2_.w, fmaf(h4.w, w3.w, acc.w))));
    }
    unsigned lo = (unsigned)f2bf(acc.x) | ((unsigned)f2bf(acc.y) << 16);
    unsigned hi = (unsigned)f2bf(acc.z) | ((unsigned)f2bf(acc.w) << 16);
    *(uint2*)&cfh[(size_t)(pb + pt_) * 128 + c4] = make_uint2(lo, hi);
  }
}

// ---------------------------------------------------------------------------
// scan: exclusive prefix over 4096 cell counts (1 block).
// ---------------------------------------------------------------------------
__global__ __launch_bounds__(256) void scan_kernel(
    const int* __restrict__ count, int* __restrict__ cellStart,
    int* __restrict__ cellofs) {
  __shared__ int part[256];
  int t = threadIdx.x;
  int local[16];
  int s = 0;
  #pragma unroll
  for (int j = 0; j < 16; ++j) { local[j] = s; s += count[t * 16 + j]; }
  part[t] = s;
  __syncthreads();
  for (int off = 1; off < 256; off <<= 1) {
    int v = (t >= off) ? part[t - off] : 0;
    __syncthreads();
    part[t] += v;
    __syncthreads();
  }
  int base = part[t] - s;
  #pragma unroll
  for (int j = 0; j < 16; ++j) {
    int v = base + local[j];
    cellStart[t * 16 + j] = v;
    cellofs[t * 16 + j] = v;
  }
  if (t == 255) cellStart[NCELL] = part[255];
}

// ---------------------------------------------------------------------------
// scatter: points + cfh rows + imfh rows into cell-sorted order.
// spts.w holds the ORIGINAL index (oid) as int bits.
// ---------------------------------------------------------------------------
__global__ __launch_bounds__(256) void scatter_kernel(
    const float4* __restrict__ pts4, const ushort_t* __restrict__ cfh,
    const ushort_t* __restrict__ imfh, int* __restrict__ cellofs,
    float4* __restrict__ spts, ushort_t* __restrict__ cfs,
    ushort_t* __restrict__ imfs) {
  __shared__ int sposl[256];
  int t = threadIdx.x;
  int pbase = blockIdx.x * 256;
  int p = pbase + t;
  float4 v = pts4[p];
  int cid = ((cellof(v.z) << 4) | cellof(v.y)) << 4 | cellof(v.x);
  int pos = atomicAdd(&cellofs[cid], 1);
  sposl[t] = pos;
  spts[pos] = make_float4(v.x, v.y, v.z, __int_as_float(p));
  __syncthreads();
  for (int e = t; e < 256 * 16; e += 256) {  // cf rows: 16 x 16B chunks
    int row = e >> 4, part = e & 15;
    *(uint4*)&cfs[(size_t)sposl[row] * 128 + part * 8] =
        *(const uint4*)&cfh[(size_t)(pbase + row) * 128 + part * 8];
  }
  for (int e = t; e < 256 * 4; e += 256) {   // imf rows: 4 x 16B chunks
    int row = e >> 2, part = e & 3;
    *(uint4*)&imfs[(size_t)sposl[row] * 32 + part * 8] =
        *(const uint4*)&imfh[(size_t)(pbase + row) * 32 + part * 8];
  }
}

// ---------------------------------------------------------------------------
// ymlp: deduplicated dense MLPs on SORTED arrays (coalesced in and out).
// ---------------------------------------------------------------------------
#define NB_LD 136
#define S1_LD 264
#define NI_LD 40
#define H1_LD 72
__global__ __launch_bounds__(256) void ymlp_kernel(
    const ushort_t* __restrict__ cfs, const ushort_t* __restrict__ imfs,
    const ushort_t* __restrict__ w1h, const float* __restrict__ b1,
    const ushort_t* __restrict__ w2h, const float* __restrict__ b2,
    const ushort_t* __restrict__ c1h, const float* __restrict__ c1b,
    const ushort_t* __restrict__ c2h, const float* __restrict__ c2b,
    ushort_t* __restrict__ ycf, ushort_t* __restrict__ yimg) {
  __shared__ ushort_t nb[64 * NB_LD];
  __shared__ ushort_t s1[64 * S1_LD];
  int t = threadIdx.x;
  int w = t >> 6, lane = t & 63;
  int col = lane & 15, quad = lane >> 4;

  if (blockIdx.x < 256) {
    int pbase = blockIdx.x * 64;
    for (int e = t; e < 1024; e += 256) {
      int row = e >> 4, c8 = (e & 15) << 3;
      *(uint4*)&nb[row * NB_LD + c8] =
          *(const uint4*)&cfs[(size_t)(pbase + row) * 128 + c8];
    }
    __syncthreads();
    f32x4 acc1[4][4];
    #pragma unroll
    for (int tt = 0; tt < 4; ++tt)
      #pragma unroll
      for (int p = 0; p < 4; ++p) acc1[tt][p] = (f32x4){0.f, 0.f, 0.f, 0.f};
    for (int k0 = 0; k0 < 128; k0 += 32) {
      bf16x8 a[4];
      #pragma unroll
      for (int p = 0; p < 4; ++p)
        a[p] = *(const bf16x8*)&nb[(p * 16 + col) * NB_LD + k0 + quad * 8];
      #pragma unroll
      for (int tt = 0; tt < 4; ++tt) {
        int n = w * 64 + tt * 16 + col;
        bf16x8 b = *(const bf16x8*)&w1h[n * 128 + k0 + quad * 8];
        #pragma unroll
        for (int p = 0; p < 4; ++p)
          acc1[tt][p] = __builtin_amdgcn_mfma_f32_16x16x32_bf16(a[p], b, acc1[tt][p], 0, 0, 0);
      }
    }
    #pragma unroll
    for (int tt = 0; tt < 4; ++tt) {
      int n = w * 64 + tt * 16 + col;
      float bb = b1[n];
      #pragma unroll
      for (int p = 0; p < 4; ++p)
        #pragma unroll
        for (int r = 0; r < 4; ++r)
          s1[(p * 16 + quad * 4 + r) * S1_LD + n] = f2bf(lrelu(acc1[tt][p][r] + bb));
    }
    __syncthreads();
    f32x4 acc2[2][4];
    #pragma unroll
    for (int tt = 0; tt < 2; ++tt)
      #pragma unroll
      for (int p = 0; p < 4; ++p) acc2[tt][p] = (f32x4){0.f, 0.f, 0.f, 0.f};
    for (int k0 = 0; k0 < 256; k0 += 32) {
      bf16x8 a[4];
      #pragma unroll
      for (int p = 0; p < 4; ++p)
        a[p] = *(const bf16x8*)&s1[(p * 16 + col) * S1_LD + k0 + quad * 8];
      #pragma unroll
      for (int tt = 0; tt < 2; ++tt) {
        int n = w * 32 + tt * 16 + col;
        bf16x8 b = *(const bf16x8*)&w2h[n * 256 + k0 + quad * 8];
        #pragma unroll
        for (int p = 0; p < 4; ++p)
          acc2[tt][p] = __builtin_amdgcn_mfma_f32_16x16x32_bf16(a[p], b, acc2[tt][p], 0, 0, 0);
      }
    }
    #pragma unroll
    for (int tt = 0; tt < 2; ++tt) {
      int n = w * 32 + tt * 16 + col;
      float bb = b2[n];
      #pragma unroll
      for (int p = 0; p < 4; ++p)
        #pragma unroll
        for (int r = 0; r < 4; ++r)
          ycf[(size_t)(pbase + p * 16 + quad * 4 + r) * 128 + n] =
              f2bf(acc2[tt][p][r] + bb);
    }
  } else {
    int pbase = (blockIdx.x - 256) * 64;
    ushort_t* nbi = nb;
    ushort_t* h1 = s1;
    {
      int row = t >> 2, c8 = (t & 3) << 3;
      *(uint4*)&nbi[row * NI_LD + c8] =
          *(const uint4*)&imfs[(size_t)(pbase + row) * 32 + c8];
    }
    __syncthreads();
    {
      f32x4 accA[4];
      #pragma unroll
      for (int p = 0; p < 4; ++p) accA[p] = (f32x4){0.f, 0.f, 0.f, 0.f};
      int n = w * 16 + col;
      bf16x8 b = *(const bf16x8*)&c1h[n * 32 + quad * 8];
      #pragma unroll
      for (int p = 0; p < 4; ++p) {
        bf16x8 a = *(const bf16x8*)&nbi[(p * 16 + col) * NI_LD + quad * 8];
        accA[p] = __builtin_amdgcn_mfma_f32_16x16x32_bf16(a, b, accA[p], 0, 0, 0);
      }
      __syncthreads();
      float bb = c1b[n];
      #pragma unroll
      for (int p = 0; p < 4; ++p)
        #pragma unroll
        for (int r = 0; r < 4; ++r)
          h1[(p * 16 + quad * 4 + r) * H1_LD + n] = f2bf(lrelu(accA[p][r] + bb));
    }
    __syncthreads();
    f32x4 acc2[2][4];
    #pragma unroll
    for (int tt = 0; tt < 2; ++tt)
      #pragma unroll
      for (int p = 0; p < 4; ++p) acc2[tt][p] = (f32x4){0.f, 0.f, 0.f, 0.f};
    for (int k0 = 0; k0 < 64; k0 += 32) {
      bf16x8 a[4];
      #pragma unroll
      for (int p = 0; p < 4; ++p)
        a[p] = *(const bf16x8*)&h1[(p * 16 + col) * H1_LD + k0 + quad * 8];
      #pragma unroll
      for (int tt = 0; tt < 2; ++tt) {
        int n = w * 32 + tt * 16 + col;
        bf16x8 b = *(const bf16x8*)&c2h[n * 64 + k0 + quad * 8];
        #pragma unroll
        for (int p = 0; p < 4; ++p)
          acc2[tt][p] = __builtin_amdgcn_mfma_f32_16x16x32_bf16(a[p], b, acc2[tt][p], 0, 0, 0);
      }
    }
    #pragma unroll
    for (int tt = 0; tt < 2; ++tt) {
      int n = w * 32 + tt * 16 + col;
      float bb = c2b[n];
      #pragma unroll
      for (int p = 0; p < 4; ++p)
        #pragma unroll
        for (int r = 0; r < 4; ++r)
          yimg[(size_t)(pbase + p * 16 + quad * 4 + r) * 128 + n] =
              f2bf(acc2[tt][p][r] + bb);
    }
  }
}

// ---------------------------------------------------------------------------
// knng_gmax: grid KNN + gather-max + feat + final GEMV, all in sorted space.
// Key = d2(32) | oid(14) | spos(14): ordering identical to (d2, oid) since
// oid unique; spos rides along as the gather index. Queries processed in
// sorted order with an XCD-contiguous block swizzle for L2 locality.
// ---------------------------------------------------------------------------
__device__ __forceinline__ u64 bsort64(u64 v, int lane) {
  #pragma unroll
  for (int k = 2; k <= 64; k <<= 1) {
    #pragma unroll
    for (int j = k >> 1; j >= 1; j >>= 1) {
      u64 p = __shfl_xor(v, j);
      bool keepmin = (((lane & j) == 0) == ((lane & k) == 0));
      u64 mn = v < p ? v : p;
      u64 mx = v < p ? p : v;
      v = keepmin ? mn : mx;
    }
  }
  return v;
}

__device__ __forceinline__ u64 compact_topk(u64* buf, int& cnt, int lane, float& tau) {
  u64 v = (lane < cnt) ? buf[lane] : ~0ULL;
  v = bsort64(v, lane);
  if (cnt > 64) {
    u64 t = (64 + lane < cnt) ? buf[64 + lane] : ~0ULL;
    t = bsort64(t, lane);
    t = __shfl_xor(t, 63);
    v = (t < v) ? t : v;
    #pragma unroll
    for (int j = 32; j >= 1; j >>= 1) {
      u64 p = __shfl_xor(v, j);
      u64 mn = v < p ? v : p;
      u64 mx = v < p ? p : v;
      v = ((lane & j) == 0) ? mn : mx;
    }
  }
  if (lane < 16) buf[lane] = v;
  cnt = 16;
  u64 k15 = __shfl(v, 15);
  tau = __uint_as_float((unsigned)(k15 >> 28));
  if (!(tau == tau)) tau = INFINITY;
  return v;
}

__device__ __forceinline__ float tadj(float tau, float qw) {
  float a = tau - qw;
  return a + fabsf(a) * 2e-7f + 1e-35f;
}

__global__ __launch_bounds__(256) void knng_kernel(
    const float4* __restrict__ spts, const int* __restrict__ cellStart,
    const ushort_t* __restrict__ ycf, const ushort_t* __restrict__ yimg,
    const ushort_t* __restrict__ cfs, const ushort_t* __restrict__ imfs,
    const float* __restrict__ fwp2, const float* __restrict__ fb,
    float* __restrict__ out) {
  __shared__ u64 sbuf[4][128];                 // 4 KB
  __shared__ alignas(16) float feat[4][416];   // 6.5 KB
  int t = threadIdx.x;
  int wv = t >> 6, lane = t & 63;
  // XCD-contiguous swizzle: consecutive blocks round-robin across XCDs, so
  // give XCD x the sorted-query slab [x*2048, (x+1)*2048).
  int sb = (blockIdx.x & 7) * 512 + (blockIdx.x >> 3);
  int s = sb * 4 + wv;  // sorted query position
  u64* buf = sbuf[wv];

  float4 q = spts[s];
  int oidq = __float_as_int(q.w);
  float qw = fmaf(q.z, q.z, fmaf(q.y, q.y, q.x * q.x));
  float q2x = -2.f * q.x, q2y = -2.f * q.y, q2z = -2.f * q.z;
  int cx = cellof(q.x), cy = cellof(q.y), cz = cellof(q.z);
  float tau = INFINITY;
  u64 vres;

  for (int r = 1;; ++r) {
    int lx = max(cx - r, 0), hx = min(cx + r, G - 1);
    int ly = max(cy - r, 0), hy = min(cy + r, G - 1);
    int lz = max(cz - r, 0), hz = min(cz + r, G - 1);
    int ny = hy - ly + 1, nz = hz - lz + 1, nruns = ny * nz;
    int cnt = 0;
    float ta = tadj(tau, qw);

    for (int rb = 0; rb < nruns; rb += 64) {
      int ln = rb + lane;
      int rs = 0, rc = 0;
      if (ln < nruns) {
        int z = lz + ln / ny, y = ly + ln % ny;
        int row = ((z << 4) | y) << 4;
        rs = cellStart[row + lx];
        rc = cellStart[row + hx + 1] - rs;
      }
      int off = rc;
      #pragma unroll
      for (int d = 1; d < 64; d <<= 1) {
        int v = __shfl_up(off, d);
        if (lane >= d) off += v;
      }
      int T = __shfl(off, 63);
      off -= rc;

      for (int cb = 0; cb < T; cb += 64) {
        int rk = cb + lane;
        int j = 0;
        #pragma unroll
        for (int step = 32; step; step >>= 1) {
          int nj = j + step;
          int onj = __shfl(off, nj & 63);
          if (nj < 64 && onj <= rk) j = nj;
        }
        int src = __shfl(rs, j) + rk - __shfl(off, j);
        bool valid = rk < T;
        if (!valid) src = 0;
        float4 c = spts[src];
        float cw = fmaf(c.z, c.z, fmaf(c.y, c.y, c.x * c.x));
        float d2 = fmaf(q2x, c.x, fmaf(q2y, c.y, fmaf(q2z, c.z, cw)));
        bool pass = valid && (d2 <= ta);
        u64 mask = __ballot(pass);
        if (mask) {
          if (pass) {
            unsigned oid = (unsigned)__float_as_int(c.w);
            u64 key = ((u64)__float_as_uint(fmaxf(d2 + qw, 0.f)) << 28) |
                      ((u64)oid << 14) | (unsigned)src;
            buf[cnt + lanerank(mask)] = key;
          }
          cnt += __popcll(mask);
          if (cnt > 64) {
            compact_topk(buf, cnt, lane, tau);
            ta = tadj(tau, qw);
          }
        }
      }
    }
    u64 v = compact_topk(buf, cnt, lane, tau);
    float cl = INFINITY;
    if (lx > 0)     cl = fminf(cl, q.x - (float)lx / (float)G);
    if (hx < G - 1) cl = fminf(cl, (float)(hx + 1) / (float)G - q.x);
    if (ly > 0)     cl = fminf(cl, q.y - (float)ly / (float)G);
    if (hy < G - 1) cl = fminf(cl, (float)(hy + 1) / (float)G - q.y);
    if (lz > 0)     cl = fminf(cl, q.z - (float)lz / (float)G);
    if (hz < G - 1) cl = fminf(cl, (float)(hz + 1) / (float)G - q.z);
    bool full = (lx == 0 && hx == G - 1 && ly == 0 && hy == G - 1 &&
                 lz == 0 && hz == G - 1);
    if (full || tau * 1.00002f <= cl * cl) { vres = v; break; }
  }

  // ---- softmax weights (lanes 0-15 hold exact top-16) ----
  int myspos = (lane < KNN) ? (int)(vres & 0x3FFF) : 0;
  float mywg = 0.f;
  {
    float4 c = spts[myspos];
    float dx = q.x - c.x, dy = q.y - c.y, dz = q.z - c.z;
    float dist = sqrtf(fmaxf(dx * dx + dy * dy + dz * dz, 1e-12f));
    float md = (lane < KNN) ? dist : INFINITY;
    #pragma unroll
    for (int off = 1; off < KNN; off <<= 1) md = fminf(md, __shfl_xor(md, off));
    float e = expf(md - dist);
    float se = (lane < KNN) ? e : 0.f;
    #pragma unroll
    for (int off = 1; off < KNN; off <<= 1) se += __shfl_xor(se, off);
    mywg = e / se;  // valid on lanes < 16
  }

  // ---- gather-max over sorted y rows (spatially local) ----
  int ksub = lane >> 4, c8 = lane & 15;
  float vimf = (lane < 32) ? bf2f(imfs[(size_t)s * 32 + lane]) : 0.f;
  unsigned vcf = *(const unsigned*)&cfs[(size_t)s * 128 + lane * 2];

  float a0[8], a1[8];
  #pragma unroll
  for (int j = 0; j < 8; ++j) { a0[j] = -INFINITY; a1[j] = -INFINITY; }
  #pragma unroll
  for (int kk = 0; kk < 4; ++kk) {
    int k = kk * 4 + ksub;
    int id = __shfl(myspos, k);
    float wg = __shfl(mywg, k);
    uint4 v = *(const uint4*)&ycf[(size_t)id * 128 + c8 * 8];
    uint4 u = *(const uint4*)&yimg[(size_t)id * 128 + c8 * 8];
    unsigned vv[4] = {v.x, v.y, v.z, v.w};
    unsigned uu[4] = {u.x, u.y, u.z, u.w};
    #pragma unroll
    for (int h = 0; h < 4; ++h) {
      a0[h * 2]     = fmaxf(a0[h * 2],     bf2f((ushort_t)(vv[h] & 0xffff)) * wg);
      a0[h * 2 + 1] = fmaxf(a0[h * 2 + 1], bf2f((ushort_t)(vv[h] >> 16)) * wg);
      a1[h * 2]     = fmaxf(a1[h * 2],     bf2f((ushort_t)(uu[h] & 0xffff)) * wg);
      a1[h * 2 + 1] = fmaxf(a1[h * 2 + 1], bf2f((ushort_t)(uu[h] >> 16)) * wg);
    }
  }
  #pragma unroll
  for (int j = 0; j < 8; ++j) {
    a0[j] = fmaxf(a0[j], __shfl_xor(a0[j], 16));
    a0[j] = fmaxf(a0[j], __shfl_xor(a0[j], 32));
    a1[j] = fmaxf(a1[j], __shfl_xor(a1[j], 16));
    a1[j] = fmaxf(a1[j], __shfl_xor(a1[j], 32));
  }
  if (lane < 16) {
    #pragma unroll
    for (int j = 0; j < 8; ++j) {
      feat[wv][c8 * 8 + j] = lrelu(a0[j]);        // sfp -> [0,128)
      feat[wv][160 + c8 * 8 + j] = lrelu(a1[j]);  // sf  -> [160,288)
    }
  }
  if (lane < 32) feat[wv][128 + lane] = lrelu(vimf);
  feat[wv][288 + lane * 2] = lrelu(bf2f((ushort_t)(vcf & 0xffff)));
  feat[wv][288 + lane * 2 + 1] = lrelu(bf2f((ushort_t)(vcf >> 16)));
  // same-wave LDS producer/consumer: no barrier needed

  // ---- final GEMV (coalesced fwp2) ----
  int ch = lane & 31, half = lane >> 5;
  float acc = half ? 0.f : fb[ch];
  const float* wr = fwp2 + (half * 52) * 128 + ch * 4;
  const float* fr = &feat[wv][half * 208];
  #pragma unroll 4
  for (int j4 = 0; j4 < 52; ++j4) {
    float4 w4 = *(const float4*)(wr + j4 * 128);
    float4 f4 = *(const float4*)(fr + j4 * 4);
    acc = fmaf(f4.x, w4.x, fmaf(f4.y, w4.y, fmaf(f4.z, w4.z, fmaf(f4.w, w4.w, acc))));
  }
  acc += __shfl_xor(acc, 32);
  if (lane < 32) out[(size_t)ch * N + oidq] = acc;
}

// ---------------------------------------------------------------------------
extern "C" void kernel_launch(void* const* d_in, const int* in_sizes, int n_in,
                              void* d_out, int out_size, void* d_ws, size_t ws_size,
                              hipStream_t stream) {
  const float* img   = (const float*)d_in[0];
  const float* cloud = (const float*)d_in[1];
  const float* c1w   = (const float*)d_in[2];
  const float* c1b   = (const float*)d_in[3];
  const float* c2w   = (const float*)d_in[4];
  const float* c2b   = (const float*)d_in[5];
  const float* ps1w  = (const float*)d_in[6];
  const float* ps1b  = (const float*)d_in[7];
  const float* ps2w  = (const float*)d_in[8];
  const float* ps2b  = (const float*)d_in[9];
  const float* p1w   = (const float*)d_in[10];
  const float* p1b   = (const float*)d_in[11];
  const float* p2w   = (const float*)d_in[12];
  const float* p2b   = (const float*)d_in[13];
  const float* fw    = (const float*)d_in[14];
  const float* fb    = (const float*)d_in[15];
  float* out = (float*)d_out;

  char* ws = (char*)d_ws;
  float4*   pts4  = (float4*)(ws + 0);             // 256 KB
  ushort_t* cfh   = (ushort_t*)(ws + 262144);      // 4 MB
  ushort_t* imfh  = (ushort_t*)(ws + 4456448);     // 1 MB
  ushort_t* w1h   = (ushort_t*)(ws + 5505024);     // 64 KB
  ushort_t* w2h   = (ushort_t*)(ws + 5570560);     // 64 KB
  ushort_t* c1h   = (ushort_t*)(ws + 5636096);     // 4 KB
  ushort_t* c2h   = (ushort_t*)(ws + 5640192);     // 16 KB
  ushort_t* ycf   = (ushort_t*)(ws + 5656576);     // 4 MB
  ushort_t* yimg  = (ushort_t*)(ws + 9850880);     // 4 MB
  float4*   spts  = (float4*)(ws + 14045184);      // 256 KB
  ushort_t* cfs   = (ushort_t*)(ws + 14307328);    // 4 MB
  ushort_t* imfs  = (ushort_t*)(ws + 18501632);    // 1 MB
  int*      cellStart = (int*)(ws + 19550208);     // 32 KB (4097 used)
  int*      cellofs   = (int*)(ws + 19582976);     // 16 KB
  int*      count     = (int*)(ws + 19599360);     // 16 KB
  float*    fwp2      = (float*)(ws + 19615744);   // 53 KB

  hipMemsetAsync(count, 0, NCELL * sizeof(int), stream);
  prepw_kernel<<<604, 256, 0, stream>>>(img, cloud, p1w, p1b, p2w, p2b,
                                        ps1w, ps2w, c1w, c2w, fw,
                                        pts4, cfh, imfh, w1h, w2h, c1h, c2h,
                                        fwp2, count);
  scan_kernel<<<1, 256, 0, stream>>>(count, cellStart, cellofs);
  scatter_kernel<<<64, 256, 0, stream>>>(pts4, cfh, imfh, cellofs,
                                         spts, cfs, imfs);
  ymlp_kernel<<<512, 256, 0, stream>>>(cfs, imfs, w1h, ps1b, w2h, ps2b,
                                       c1h, c1b, c2h, c2b, ycf, yimg);
  knng_kernel<<<N / 4, 256, 0, stream>>>(spts, cellStart, ycf, yimg,
                                         cfs, imfs, fwp2, fb, out);
}